// Round 22
// baseline (42.504 us; speedup 1.0000x reference)
//
#include <hip/hip_runtime.h>
#include <hip/hip_bf16.h>

#define NPIX 9216
#define CIN 64
#define ICH 32
#define LOG2E 1.4426950408889634f

typedef float f32x4 __attribute__((ext_vector_type(4)));
typedef short bf16x8 __attribute__((ext_vector_type(8)));

#if __has_builtin(__builtin_amdgcn_exp2f)
#define EXP2(x) __builtin_amdgcn_exp2f(x)
#else
#define EXP2(x) exp2f(x)
#endif

// async global->LDS, 16B per lane, dest = wave-uniform base + lane*16
#define GLLDS(gp, lp) \
  __builtin_amdgcn_global_load_lds( \
      (const __attribute__((address_space(1))) unsigned int*)(gp), \
      (__attribute__((address_space(3))) unsigned int*)(lp), 16, 0, 0)

static __device__ __forceinline__ unsigned short f2bf(float f) {
  union { float f; unsigned u; } v; v.f = f;
  unsigned u = v.u;
  u = u + 0x7FFFu + ((u >> 16) & 1u);
  return (unsigned short)(u >> 16);
}

// ---------------- Kernel A: three 1x1 projections -> bf16 buffers ----------
// 48 (proj, 2-ch slice) groups x 36 pixel-subs = 1728 blocks = 6.75/CU
// (r21 was 864 = 3.375/CU). Writes identical elements in identical layouts.
__global__ __launch_bounds__(256) void proj_kernel(
    const float* __restrict__ x,
    const float* __restrict__ Wt, const float* __restrict__ bt,
    const float* __restrict__ Wp, const float* __restrict__ bp,
    const float* __restrict__ Wg, const float* __restrict__ bg,
    unsigned short* __restrict__ theta,
    unsigned short* __restrict__ phiT,
    unsigned short* __restrict__ vTs,
    float* __restrict__ zbuf)          // pacc+pl region: 304128 floats
{
  const int sub  = blockIdx.x % 36;
  const int grp  = blockIdx.x / 36;      // 0..47, uniform per block
  const int proj = grp >> 4;             // 0..2
  const int og   = (grp & 15) * 2;       // 0,2,..,30
  const int m    = sub * 256 + threadIdx.x;

  // zero the partial buffers (76032 float4s over 442368 threads)
  const int t = blockIdx.x * 256 + threadIdx.x;
  if (t < 76032) {
    const f32x4 z4 = {0.f, 0.f, 0.f, 0.f};
    reinterpret_cast<f32x4*>(zbuf)[t] = z4;
  }

  const float* W; const float* bias;
  if (proj == 0)      { W = Wt; bias = bt; }
  else if (proj == 1) { W = Wp; bias = bp; }
  else                { W = Wg; bias = bg; }

  float acc0 = bias[og], acc1 = bias[og + 1];
  for (int c = 0; c < CIN; ++c) {
    float xv = x[c * NPIX + m];
    acc0 = fmaf(W[og * CIN + c],       xv, acc0);
    acc1 = fmaf(W[(og + 1) * CIN + c], xv, acc1);
  }

  if (proj == 0) {
    theta[og * NPIX + m]       = f2bf(acc0 * LOG2E);
    theta[(og + 1) * NPIX + m] = f2bf(acc1 * LOG2E);
  } else if (proj == 1) {
    unsigned pk = (unsigned)f2bf(acc0) | ((unsigned)f2bf(acc1) << 16);
    *reinterpret_cast<unsigned*>(phiT + m * ICH + og) = pk;   // 4B aligned
  } else {
#pragma unroll
    for (int o = 0; o < 2; ++o) {
      float av = (o == 0) ? acc0 : acc1;
      int n = 288 * (og + o) + (m >> 5);       // V row index (reshape identity)
      int k = n & 31;
      int p = ((k >> 2) & 3) * 8 + ((k >> 4) << 2) + (k & 3);  // nu-inverse
      vTs[(m & 31) * NPIX + (n & ~31) + p] = f2bf(av);
    }
  }
}

// ---------------- Kernel B: flash attention, LDS-staged, split-K=16 --------
// EXACT r17/r20/r21 kernel. 2304 blocks (8 co-resident blocks/CU = 32-wave
// cap), 4 waves x 16 q, 576 keys in 9 chunks x 64, double-buffered 16KB LDS,
// split accumulators.
__global__ __launch_bounds__(256) void attn_kernel(
    const unsigned short* __restrict__ theta,
    const unsigned short* __restrict__ phiT,
    const unsigned short* __restrict__ vTs,
    float* __restrict__ pacc, float* __restrict__ pl)
{
  __shared__ __align__(16) unsigned char lds[2][8192];

  const int tid = threadIdx.x;
  const int l   = tid & 63;
  const int w   = tid >> 6;          // 0..3
  const int r16 = l & 15;
  const int g   = l >> 4;
  const int qt    = blockIdx.x >> 4;       // 0..143
  const int split = blockIdx.x & 15;       // 0..15
  const int qbase = qt * 64 + w * 16;
  const int keybase = split * 576;
  const int cbase = (unsigned)(qt * 5 + split) % 9;   // de-lockstep (sums commute)

  // Q fragment: lane holds Q[q=qbase+r16][ch 8g..8g+7] (theta pre-scaled LOG2E)
  bf16x8 qf = *reinterpret_cast<const bf16x8*>(theta + (qbase + r16) * ICH + 8 * g);

  f32x4 accA0 = {0.f, 0.f, 0.f, 0.f}, accA1 = {0.f, 0.f, 0.f, 0.f};
  f32x4 accB0 = {0.f, 0.f, 0.f, 0.f}, accB1 = {0.f, 0.f, 0.f, 0.f};
  const f32x4 z4 = {0.f, 0.f, 0.f, 0.f};
  float l_run = 0.f;

  // ---- staging: one chunk = 8KB (K 4KB + V 4KB), 2 issues/thread ----
  auto stage = [&](int buf, int cc) {
    unsigned char* Lb = &lds[buf][0];
    const int key0 = keybase + cc * 64;
    if (w < 2) {
      // K: 16-key groups j=0..3 contiguous; ch-slot permuted gp=(l&3)^(k&3)
      const int k  = (l >> 2);
      const int gp = (l & 3) ^ (k & 3);
#pragma unroll
      for (int i = 0; i < 2; ++i) {
        const int j = w * 2 + i;                    // 16-key group 0..3
        GLLDS(phiT + (key0 + j * 16 + k) * ICH + gp * 8, Lb + j * 1024);
      }
    } else {
      // V: rows d (128B each), key-slot permuted sl=(l&7)^(d&7)
#pragma unroll
      for (int i = 0; i < 2; ++i) {
        const int dg = (w - 2) * 2 + i;             // 8-row group 0..3
        const int d  = dg * 8 + (l >> 3);
        const int sl = (l & 7) ^ (d & 7);
        GLLDS(vTs + d * NPIX + key0 + sl * 8, Lb + 4096 + dg * 1024);
      }
    }
  };

  // ---- one 32-key step from LDS (read swizzles verbatim r12/r17) ----
  auto step = [&](const unsigned char* Lb, int st, f32x4& a0, f32x4& a1) {
    const int kk = st * 32 + r16;
    const int kx = (g ^ (kk & 3)) << 4;             // K read swizzle
    const bf16x8 kf0 = *reinterpret_cast<const bf16x8*>(Lb + kk * 64 + kx);
    const bf16x8 kf1 = *reinterpret_cast<const bf16x8*>(Lb + (kk + 16) * 64 + kx);
    const int sp = ((st * 4 + g) ^ (r16 & 7)) * 16; // V read swizzle
    const bf16x8 vf0 = *reinterpret_cast<const bf16x8*>(Lb + 4096 + r16 * 128 + sp);
    const bf16x8 vf1 = *reinterpret_cast<const bf16x8*>(Lb + 4096 + (16 + r16) * 128 + sp);

    f32x4 cs0 = __builtin_amdgcn_mfma_f32_16x16x32_bf16(kf0, qf, z4, 0, 0, 0);
    f32x4 cs1 = __builtin_amdgcn_mfma_f32_16x16x32_bf16(kf1, qf, z4, 0, 0, 0);

    float p[8]; float psum = 0.f;
#pragma unroll
    for (int j = 0; j < 4; ++j) { p[j] = EXP2(cs0[j]); psum += p[j]; }
#pragma unroll
    for (int j = 0; j < 4; ++j) { p[4 + j] = EXP2(cs1[j]); psum += p[4 + j]; }
    l_run += psum;

    union { unsigned u[4]; bf16x8 v; } pk;
#pragma unroll
    for (int j = 0; j < 4; ++j) {
      asm("v_cvt_pk_bf16_f32 %0, %1, %2" : "=v"(pk.u[j]) : "v"(p[2 * j]), "v"(p[2 * j + 1]));
    }

    a0 = __builtin_amdgcn_mfma_f32_16x16x32_bf16(pk.v, vf0, a0, 0, 0, 0);
    a1 = __builtin_amdgcn_mfma_f32_16x16x32_bf16(pk.v, vf1, a1, 0, 0, 0);
  };

  // ---- 2-phase double-buffered main loop ----
  stage(0, cbase);
  __syncthreads();                 // compiler drains vmcnt before s_barrier
  int cur = 0;
#pragma unroll 1
  for (int c = 0; c < 9; ++c) {
    if (c + 1 < 9) {
      int cn = cbase + c + 1; if (cn >= 9) cn -= 9;
      stage(cur ^ 1, cn);
    }
    step(&lds[cur][0], 0, accA0, accA1);   // independent acc chains A/B
    step(&lds[cur][0], 1, accB0, accB1);
    __syncthreads();               // stage landed + all waves done with cur
    cur ^= 1;
  }

  f32x4 acc0 = accA0 + accB0;
  f32x4 acc1 = accA1 + accB1;

  // ---- epilogue: reduce l over the 4 lane-replicas, atomic-merge splits ----
  l_run += __shfl_xor(l_run, 16);
  l_run += __shfl_xor(l_run, 32);

#pragma unroll
  for (int j = 0; j < 4; ++j) {
    const int q = qbase + 4 * g + j;
    atomicAdd(&pacc[q * ICH + r16],      acc0[j]);
    atomicAdd(&pacc[q * ICH + 16 + r16], acc1[j]);
  }
  if (g == 0) atomicAdd(&pl[qbase + r16], l_run);
}

// ---------------- Kernel B2: z = pacc/pl, second softmax over 32 ch --------
// (r11 exact)
__global__ __launch_bounds__(256) void merge_kernel(
    const float* __restrict__ pacc, const float* __restrict__ pl,
    float* __restrict__ ybuf)
{
  const int q  = blockIdx.x * 8 + (threadIdx.x >> 5);
  const int ch = threadIdx.x & 31;

  float z  = pacc[q * ICH + ch] / pl[q];
  float zl = z * LOG2E;
  float zm = zl;
#pragma unroll
  for (int k = 1; k < 32; k <<= 1) zm = fmaxf(zm, __shfl_xor(zm, k));
  float e = EXP2(zl - zm);
  float ss = e;
#pragma unroll
  for (int k = 1; k < 32; k <<= 1) ss += __shfl_xor(ss, k);
  ybuf[q * ICH + ch] = e / ss;
}

// ---------------- Kernel C: out = Wo*y + bo + x ----------------------------
// (r20/r21 proven: 1152 blocks, 2 channels/block, 4.5 blocks/CU)
__global__ __launch_bounds__(256) void out_kernel(
    const float* __restrict__ x, const float* __restrict__ Wo,
    const float* __restrict__ bo, const float* __restrict__ ybuf,
    float* __restrict__ out)
{
  const int sub = blockIdx.x % 36;
  const int o0  = (blockIdx.x / 36) * 2;   // uniform per block, 0..62
  const int s   = sub * 256 + threadIdx.x;

  float acc0 = 0.f, acc1 = 0.f;
#pragma unroll
  for (int c = 0; c < ICH; ++c) {
    float yv = ybuf[c * NPIX + s];   // flat reinterpretation, like reference
    acc0 = fmaf(Wo[o0 * ICH + c],       yv, acc0);
    acc1 = fmaf(Wo[(o0 + 1) * ICH + c], yv, acc1);
  }
  out[o0 * NPIX + s]       = acc0 + bo[o0]     + x[o0 * NPIX + s];
  out[(o0 + 1) * NPIX + s] = acc1 + bo[o0 + 1] + x[(o0 + 1) * NPIX + s];
}

extern "C" void kernel_launch(void* const* d_in, const int* in_sizes, int n_in,
                              void* d_out, int out_size, void* d_ws, size_t ws_size,
                              hipStream_t stream) {
  const float* x  = (const float*)d_in[0];
  const float* Wt = (const float*)d_in[1];
  const float* bt = (const float*)d_in[2];
  const float* Wp = (const float*)d_in[3];
  const float* bp = (const float*)d_in[4];
  const float* Wg = (const float*)d_in[5];
  const float* bg = (const float*)d_in[6];
  const float* Wo = (const float*)d_in[7];
  const float* bo = (const float*)d_in[8];
  float* out = (float*)d_out;

  char* ws = (char*)d_ws;
  unsigned short* theta = (unsigned short*)(ws);               // [0, 589824)
  unsigned short* phiT  = (unsigned short*)(ws + 589824);      // [589824, 1179648)
  unsigned short* vTs   = (unsigned short*)(ws + 1179648);     // [1179648, 1769472)
  float* pacc = (float*)(ws + 1769472);                        // [1769472, 2949120)
  float* pl   = (float*)(ws + 2949120);                        // [2949120, 2985984)
  float* ybuf = (float*)(ws);                                  // overlaps theta/phiT (dead after attn)

  proj_kernel<<<1728, 256, 0, stream>>>(x, Wt, bt, Wp, bp, Wg, bg, theta, phiT, vTs, pacc);
  attn_kernel<<<2304, 256, 0, stream>>>(theta, phiT, vTs, pacc, pl);
  merge_kernel<<<1152, 256, 0, stream>>>(pacc, pl, ybuf);
  out_kernel<<<1152, 256, 0, stream>>>(x, Wo, bo, ybuf, out);
}

// Round 23
// 42.054 us; speedup vs baseline: 1.0107x; 1.0107x over previous
//
#include <hip/hip_runtime.h>
#include <hip/hip_bf16.h>

#define NPIX 9216
#define CIN 64
#define ICH 32
#define LOG2E 1.4426950408889634f

typedef float f32x4 __attribute__((ext_vector_type(4)));
typedef short bf16x8 __attribute__((ext_vector_type(8)));

#if __has_builtin(__builtin_amdgcn_exp2f)
#define EXP2(x) __builtin_amdgcn_exp2f(x)
#else
#define EXP2(x) exp2f(x)
#endif

// async global->LDS, 16B per lane, dest = wave-uniform base + lane*16
#define GLLDS(gp, lp) \
  __builtin_amdgcn_global_load_lds( \
      (const __attribute__((address_space(1))) unsigned int*)(gp), \
      (__attribute__((address_space(3))) unsigned int*)(lp), 16, 0, 0)

static __device__ __forceinline__ unsigned short f2bf(float f) {
  union { float f; unsigned u; } v; v.f = f;
  unsigned u = v.u;
  u = u + 0x7FFFu + ((u >> 16) & 1u);
  return (unsigned short)(u >> 16);
}

// ---------------- Kernel A: three 1x1 projections -> bf16 buffers ----------
// (r21 best: 24 (proj, 4-ch slice) groups x 36 pixel-subs = 864 blocks,
//  3.375 blocks/CU; zeroes pacc/pl in-kernel)
__global__ __launch_bounds__(256) void proj_kernel(
    const float* __restrict__ x,
    const float* __restrict__ Wt, const float* __restrict__ bt,
    const float* __restrict__ Wp, const float* __restrict__ bp,
    const float* __restrict__ Wg, const float* __restrict__ bg,
    unsigned short* __restrict__ theta,
    unsigned short* __restrict__ phiT,
    unsigned short* __restrict__ vTs,
    float* __restrict__ zbuf)          // pacc+pl region: 304128 floats
{
  const int sub  = blockIdx.x % 36;
  const int grp  = blockIdx.x / 36;      // 0..23, uniform per block
  const int proj = grp >> 3;             // 0..2
  const int og   = (grp & 7) * 4;        // 0,4,..,28
  const int m    = sub * 256 + threadIdx.x;

  // zero the partial buffers (76032 float4s over 221184 threads)
  const int t = blockIdx.x * 256 + threadIdx.x;
  if (t < 76032) {
    const f32x4 z4 = {0.f, 0.f, 0.f, 0.f};
    reinterpret_cast<f32x4*>(zbuf)[t] = z4;
  }

  const float* W; const float* bias;
  if (proj == 0)      { W = Wt; bias = bt; }
  else if (proj == 1) { W = Wp; bias = bp; }
  else                { W = Wg; bias = bg; }

  float acc[4];
#pragma unroll
  for (int o = 0; o < 4; ++o) acc[o] = bias[og + o];
  for (int c = 0; c < CIN; ++c) {
    float xv = x[c * NPIX + m];
#pragma unroll
    for (int o = 0; o < 4; ++o) acc[o] = fmaf(W[(og + o) * CIN + c], xv, acc[o]);
  }

  if (proj == 0) {
#pragma unroll
    for (int o = 0; o < 4; ++o) theta[(og + o) * NPIX + m] = f2bf(acc[o] * LOG2E);
  } else if (proj == 1) {
    union { unsigned short s[4]; unsigned long long v; } pk;
#pragma unroll
    for (int o = 0; o < 4; ++o) pk.s[o] = f2bf(acc[o]);
    *reinterpret_cast<unsigned long long*>(phiT + m * ICH + og) = pk.v;  // 8B aligned
  } else {
#pragma unroll
    for (int o = 0; o < 4; ++o) {
      int n = 288 * (og + o) + (m >> 5);       // V row index (reshape identity)
      int k = n & 31;
      int p = ((k >> 2) & 3) * 8 + ((k >> 4) << 2) + (k & 3);  // nu-inverse
      vTs[(m & 31) * NPIX + (n & ~31) + p] = f2bf(acc[o]);
    }
  }
}

// ---------------- Kernel B: flash attention, LDS-staged, split-K=16 --------
// EXACT r17/r20/r21 kernel. 2304 blocks (8 co-resident blocks/CU = 32-wave
// cap), 4 waves x 16 q, 576 keys in 9 chunks x 64, double-buffered 16KB LDS,
// split accumulators.
__global__ __launch_bounds__(256) void attn_kernel(
    const unsigned short* __restrict__ theta,
    const unsigned short* __restrict__ phiT,
    const unsigned short* __restrict__ vTs,
    float* __restrict__ pacc, float* __restrict__ pl)
{
  __shared__ __align__(16) unsigned char lds[2][8192];

  const int tid = threadIdx.x;
  const int l   = tid & 63;
  const int w   = tid >> 6;          // 0..3
  const int r16 = l & 15;
  const int g   = l >> 4;
  const int qt    = blockIdx.x >> 4;       // 0..143
  const int split = blockIdx.x & 15;       // 0..15
  const int qbase = qt * 64 + w * 16;
  const int keybase = split * 576;
  const int cbase = (unsigned)(qt * 5 + split) % 9;   // de-lockstep (sums commute)

  // Q fragment: lane holds Q[q=qbase+r16][ch 8g..8g+7] (theta pre-scaled LOG2E)
  bf16x8 qf = *reinterpret_cast<const bf16x8*>(theta + (qbase + r16) * ICH + 8 * g);

  f32x4 accA0 = {0.f, 0.f, 0.f, 0.f}, accA1 = {0.f, 0.f, 0.f, 0.f};
  f32x4 accB0 = {0.f, 0.f, 0.f, 0.f}, accB1 = {0.f, 0.f, 0.f, 0.f};
  const f32x4 z4 = {0.f, 0.f, 0.f, 0.f};
  float l_run = 0.f;

  // ---- staging: one chunk = 8KB (K 4KB + V 4KB), 2 issues/thread ----
  auto stage = [&](int buf, int cc) {
    unsigned char* Lb = &lds[buf][0];
    const int key0 = keybase + cc * 64;
    if (w < 2) {
      // K: 16-key groups j=0..3 contiguous; ch-slot permuted gp=(l&3)^(k&3)
      const int k  = (l >> 2);
      const int gp = (l & 3) ^ (k & 3);
#pragma unroll
      for (int i = 0; i < 2; ++i) {
        const int j = w * 2 + i;                    // 16-key group 0..3
        GLLDS(phiT + (key0 + j * 16 + k) * ICH + gp * 8, Lb + j * 1024);
      }
    } else {
      // V: rows d (128B each), key-slot permuted sl=(l&7)^(d&7)
#pragma unroll
      for (int i = 0; i < 2; ++i) {
        const int dg = (w - 2) * 2 + i;             // 8-row group 0..3
        const int d  = dg * 8 + (l >> 3);
        const int sl = (l & 7) ^ (d & 7);
        GLLDS(vTs + d * NPIX + key0 + sl * 8, Lb + 4096 + dg * 1024);
      }
    }
  };

  // ---- one 32-key step from LDS (read swizzles verbatim r12/r17) ----
  auto step = [&](const unsigned char* Lb, int st, f32x4& a0, f32x4& a1) {
    const int kk = st * 32 + r16;
    const int kx = (g ^ (kk & 3)) << 4;             // K read swizzle
    const bf16x8 kf0 = *reinterpret_cast<const bf16x8*>(Lb + kk * 64 + kx);
    const bf16x8 kf1 = *reinterpret_cast<const bf16x8*>(Lb + (kk + 16) * 64 + kx);
    const int sp = ((st * 4 + g) ^ (r16 & 7)) * 16; // V read swizzle
    const bf16x8 vf0 = *reinterpret_cast<const bf16x8*>(Lb + 4096 + r16 * 128 + sp);
    const bf16x8 vf1 = *reinterpret_cast<const bf16x8*>(Lb + 4096 + (16 + r16) * 128 + sp);

    f32x4 cs0 = __builtin_amdgcn_mfma_f32_16x16x32_bf16(kf0, qf, z4, 0, 0, 0);
    f32x4 cs1 = __builtin_amdgcn_mfma_f32_16x16x32_bf16(kf1, qf, z4, 0, 0, 0);

    float p[8]; float psum = 0.f;
#pragma unroll
    for (int j = 0; j < 4; ++j) { p[j] = EXP2(cs0[j]); psum += p[j]; }
#pragma unroll
    for (int j = 0; j < 4; ++j) { p[4 + j] = EXP2(cs1[j]); psum += p[4 + j]; }
    l_run += psum;

    union { unsigned u[4]; bf16x8 v; } pk;
#pragma unroll
    for (int j = 0; j < 4; ++j) {
      asm("v_cvt_pk_bf16_f32 %0, %1, %2" : "=v"(pk.u[j]) : "v"(p[2 * j]), "v"(p[2 * j + 1]));
    }

    a0 = __builtin_amdgcn_mfma_f32_16x16x32_bf16(pk.v, vf0, a0, 0, 0, 0);
    a1 = __builtin_amdgcn_mfma_f32_16x16x32_bf16(pk.v, vf1, a1, 0, 0, 0);
  };

  // ---- 2-phase double-buffered main loop ----
  stage(0, cbase);
  __syncthreads();                 // compiler drains vmcnt before s_barrier
  int cur = 0;
#pragma unroll 1
  for (int c = 0; c < 9; ++c) {
    if (c + 1 < 9) {
      int cn = cbase + c + 1; if (cn >= 9) cn -= 9;
      stage(cur ^ 1, cn);
    }
    step(&lds[cur][0], 0, accA0, accA1);   // independent acc chains A/B
    step(&lds[cur][0], 1, accB0, accB1);
    __syncthreads();               // stage landed + all waves done with cur
    cur ^= 1;
  }

  f32x4 acc0 = accA0 + accB0;
  f32x4 acc1 = accA1 + accB1;

  // ---- epilogue: reduce l over the 4 lane-replicas, atomic-merge splits ----
  l_run += __shfl_xor(l_run, 16);
  l_run += __shfl_xor(l_run, 32);

#pragma unroll
  for (int j = 0; j < 4; ++j) {
    const int q = qbase + 4 * g + j;
    atomicAdd(&pacc[q * ICH + r16],      acc0[j]);
    atomicAdd(&pacc[q * ICH + 16 + r16], acc1[j]);
  }
  if (g == 0) atomicAdd(&pl[qbase + r16], l_run);
}

// ---------------- Kernel B2: z = pacc/pl, second softmax over 32 ch --------
// (r11 exact)
__global__ __launch_bounds__(256) void merge_kernel(
    const float* __restrict__ pacc, const float* __restrict__ pl,
    float* __restrict__ ybuf)
{
  const int q  = blockIdx.x * 8 + (threadIdx.x >> 5);
  const int ch = threadIdx.x & 31;

  float z  = pacc[q * ICH + ch] / pl[q];
  float zl = z * LOG2E;
  float zm = zl;
#pragma unroll
  for (int k = 1; k < 32; k <<= 1) zm = fmaxf(zm, __shfl_xor(zm, k));
  float e = EXP2(zl - zm);
  float ss = e;
#pragma unroll
  for (int k = 1; k < 32; k <<= 1) ss += __shfl_xor(ss, k);
  ybuf[q * ICH + ch] = e / ss;
}

// ---------------- Kernel C: out = Wo*y + bo + x ----------------------------
// (r20/r21 proven: 1152 blocks, 2 channels/block, 4.5 blocks/CU)
__global__ __launch_bounds__(256) void out_kernel(
    const float* __restrict__ x, const float* __restrict__ Wo,
    const float* __restrict__ bo, const float* __restrict__ ybuf,
    float* __restrict__ out)
{
  const int sub = blockIdx.x % 36;
  const int o0  = (blockIdx.x / 36) * 2;   // uniform per block, 0..62
  const int s   = sub * 256 + threadIdx.x;

  float acc0 = 0.f, acc1 = 0.f;
#pragma unroll
  for (int c = 0; c < ICH; ++c) {
    float yv = ybuf[c * NPIX + s];   // flat reinterpretation, like reference
    acc0 = fmaf(Wo[o0 * ICH + c],       yv, acc0);
    acc1 = fmaf(Wo[(o0 + 1) * ICH + c], yv, acc1);
  }
  out[o0 * NPIX + s]       = acc0 + bo[o0]     + x[o0 * NPIX + s];
  out[(o0 + 1) * NPIX + s] = acc1 + bo[o0 + 1] + x[(o0 + 1) * NPIX + s];
}

extern "C" void kernel_launch(void* const* d_in, const int* in_sizes, int n_in,
                              void* d_out, int out_size, void* d_ws, size_t ws_size,
                              hipStream_t stream) {
  const float* x  = (const float*)d_in[0];
  const float* Wt = (const float*)d_in[1];
  const float* bt = (const float*)d_in[2];
  const float* Wp = (const float*)d_in[3];
  const float* bp = (const float*)d_in[4];
  const float* Wg = (const float*)d_in[5];
  const float* bg = (const float*)d_in[6];
  const float* Wo = (const float*)d_in[7];
  const float* bo = (const float*)d_in[8];
  float* out = (float*)d_out;

  char* ws = (char*)d_ws;
  unsigned short* theta = (unsigned short*)(ws);               // [0, 589824)
  unsigned short* phiT  = (unsigned short*)(ws + 589824);      // [589824, 1179648)
  unsigned short* vTs   = (unsigned short*)(ws + 1179648);     // [1179648, 1769472)
  float* pacc = (float*)(ws + 1769472);                        // [1769472, 2949120)
  float* pl   = (float*)(ws + 2949120);                        // [2949120, 2985984)
  float* ybuf = (float*)(ws);                                  // overlaps theta/phiT (dead after attn)

  proj_kernel<<<864, 256, 0, stream>>>(x, Wt, bt, Wp, bp, Wg, bg, theta, phiT, vTs, pacc);
  attn_kernel<<<2304, 256, 0, stream>>>(theta, phiT, vTs, pacc, pl);
  merge_kernel<<<1152, 256, 0, stream>>>(pacc, pl, ybuf);
  out_kernel<<<1152, 256, 0, stream>>>(x, Wo, bo, ybuf, out);
}